// Round 1
// baseline (825.953 us; speedup 1.0000x reference)
//
#include <hip/hip_runtime.h>
#include <hip/hip_bf16.h>
#include <stdint.h>

// GGUF Q8_0-style quantized linear: C[M,N] = A[M,K] * W[K,N] + bias[N]
//   W[k][n] = q[k][n] * scales[k][n>>5]   (q: int8 codes stored as int32)
// M = B*S = 8192, K = IN = 4096, N = OUT = 4096.
// Strategy: fused dequant -> bf16 MFMA GEMM (16x16x32), 128x128 tile, BK=32.

#define M_DIM 8192
#define N_DIM 4096
#define K_DIM 4096
#define NBLK  128   // N / 32 (scale blocks per row)
#define BM 128
#define BN 128
#define BK 32

typedef __attribute__((ext_vector_type(8))) short short8;   // 8 bf16 = 4 VGPRs
typedef __attribute__((ext_vector_type(4))) float f32x4;    // MFMA accumulator

// Pack two fp32 into two bf16 (RNE) in one dword: low = a, high = b.
__device__ __forceinline__ unsigned pk_bf16(float a, float b) {
  unsigned ua = __builtin_bit_cast(unsigned, a);
  unsigned ub = __builtin_bit_cast(unsigned, b);
  ua += 0x7fffu + ((ua >> 16) & 1u);
  ub += 0x7fffu + ((ub >> 16) & 1u);
  return (ua >> 16) | (ub & 0xffff0000u);
}

// LDS layout: row-major [row][k], 32 ushorts per row, with XOR swizzle on the
// 8-element k-group: k' = k ^ (((row>>1)&3)<<3). Keeps ds_*_b128 16B-aligned
// and spreads both staging writes and fragment reads across all 32 banks.

__global__ __launch_bounds__(256)
void gguf_gemm(const float* __restrict__ A,
               const int*   __restrict__ Q,
               const float* __restrict__ S,
               const float* __restrict__ bias,
               float*       __restrict__ C) {
  __shared__ __align__(16) ushort Alds[BM * BK];
  __shared__ __align__(16) ushort Blds[BN * BK];

  const int tid = threadIdx.x;
  const int m0 = blockIdx.y * BM;
  const int n0 = blockIdx.x * BN;

  const int wave = tid >> 6;
  const int lane = tid & 63;
  const int wm = (wave >> 1) * 64;   // wave's m-offset inside tile
  const int wn = (wave & 1) * 64;    // wave's n-offset inside tile
  const int lrow = lane & 15;
  const int quad = lane >> 4;

  // ---- A staging mapping: thread -> (row ar(+64), k-chunk ac + j*16), float4 each
  const int ar = tid >> 2;          // 0..63
  const int ac = (tid & 3) * 4;     // 0,4,8,12
  const int c8a = ((ar >> 1) & 3) << 3;   // same for row ar+64 (bit pattern preserved)

  // ---- B staging mapping: thread -> column n (coalesced across lanes), 16 k's
  const int bn  = tid & 127;          // 0..127
  const int bkc = (tid >> 7) * 16;    // 0 or 16
  const int c8b = ((bn >> 1) & 3) << 3;

  const float* Abase = A + (long)(m0 + ar) * K_DIM + ac;
  const int*   Qbase = Q + (long)bkc * N_DIM + n0 + bn;
  const float* Sbase = S + (long)bkc * NBLK + ((n0 + bn) >> 5);

  f32x4 acc[4][4];
  #pragma unroll
  for (int i = 0; i < 4; ++i)
    #pragma unroll
    for (int j = 0; j < 4; ++j)
      acc[i][j] = (f32x4){0.f, 0.f, 0.f, 0.f};

  for (int k0 = 0; k0 < K_DIM; k0 += BK) {
    // ---- stage A: 128x32 fp32 -> bf16 into Alds
    #pragma unroll
    for (int i = 0; i < 2; ++i) {
      #pragma unroll
      for (int j = 0; j < 2; ++j) {
        const float4 v = *(const float4*)(Abase + (long)i * 64 * K_DIM + k0 + j * 16);
        uint2 p;
        p.x = pk_bf16(v.x, v.y);
        p.y = pk_bf16(v.z, v.w);
        const int k = ac + j * 16;
        *(uint2*)&Alds[(ar + i * 64) * 32 + (k ^ c8a)] = p;
      }
    }
    // ---- stage B: dequant 32x128 q*scale -> bf16, transposed into Blds[n][k]
    {
      const int*   qp = Qbase + (long)k0 * N_DIM;
      const float* sp = Sbase + (long)k0 * NBLK;
      unsigned w[8];
      #pragma unroll
      for (int i = 0; i < 8; ++i) {
        const int   q0 = qp[(2 * i) * N_DIM];
        const int   q1 = qp[(2 * i + 1) * N_DIM];
        const float s0 = sp[(2 * i) * NBLK];
        const float s1 = sp[(2 * i + 1) * NBLK];
        w[i] = pk_bf16((float)q0 * s0, (float)q1 * s1);
      }
      uint4 g0 = {w[0], w[1], w[2], w[3]};
      uint4 g1 = {w[4], w[5], w[6], w[7]};
      *(uint4*)&Blds[bn * 32 + (bkc ^ c8b)] = g0;
      *(uint4*)&Blds[bn * 32 + ((bkc + 8) ^ c8b)] = g1;
    }
    __syncthreads();

    // ---- fragments + 16 MFMA per wave
    short8 afrag[4], bfrag[4];
    #pragma unroll
    for (int t = 0; t < 4; ++t) {
      const int mrow = wm + t * 16 + lrow;
      afrag[t] = *(const short8*)&Alds[mrow * 32 + ((quad * 8) ^ (((mrow >> 1) & 3) << 3))];
      const int nrow = wn + t * 16 + lrow;
      bfrag[t] = *(const short8*)&Blds[nrow * 32 + ((quad * 8) ^ (((nrow >> 1) & 3) << 3))];
    }
    #pragma unroll
    for (int mt = 0; mt < 4; ++mt)
      #pragma unroll
      for (int nt = 0; nt < 4; ++nt)
        acc[mt][nt] = __builtin_amdgcn_mfma_f32_16x16x32_bf16(afrag[mt], bfrag[nt],
                                                              acc[mt][nt], 0, 0, 0);

    __syncthreads();
  }

  // ---- epilogue: C[m][n] = acc + bias[n]  (C/D layout: row=quad*4+reg, col=lane&15)
  #pragma unroll
  for (int nt = 0; nt < 4; ++nt) {
    const int n = n0 + wn + nt * 16 + lrow;
    const float bv = bias[n];
    #pragma unroll
    for (int mt = 0; mt < 4; ++mt) {
      const int mbase = m0 + wm + mt * 16 + quad * 4;
      #pragma unroll
      for (int r = 0; r < 4; ++r) {
        C[(long)(mbase + r) * N_DIM + n] = acc[mt][nt][r] + bv;
      }
    }
  }
}

extern "C" void kernel_launch(void* const* d_in, const int* in_sizes, int n_in,
                              void* d_out, int out_size, void* d_ws, size_t ws_size,
                              hipStream_t stream) {
  const float* A    = (const float*)d_in[0];   // input  [2,4096,4096] fp32
  const int*   Q    = (const int*)d_in[1];     // qweight [4096,4096] int32 (int8 codes)
  const float* S    = (const float*)d_in[2];   // scales [4096,128] fp32
  const float* bias = (const float*)d_in[3];   // bias [4096] fp32
  float* C = (float*)d_out;                    // out [2,4096,4096] fp32

  dim3 grid(N_DIM / BN, M_DIM / BM);           // (32, 64)
  gguf_gemm<<<grid, 256, 0, stream>>>(A, Q, S, bias, C);
}

// Round 2
// 574.295 us; speedup vs baseline: 1.4382x; 1.4382x over previous
//
#include <hip/hip_runtime.h>
#include <hip/hip_bf16.h>
#include <stdint.h>

// GGUF Q8_0-style quantized linear: C[M,N] = A[M,K] * W[K,N] + bias[N]
//   W[k][n] = q[k][n] * scales[k][n>>5]
// M = 8192, K = 4096, N = 4096.
//
// Two-pass strategy:
//   pass 1a: A fp32 -> bf16 (workspace)          ~201 MB traffic
//   pass 1b: dequant + transpose W -> Wt[N][K] bf16 (workspace)  ~101 MB
//   pass 2:  m97-structure bf16 MFMA GEMM (global_load_lds width=16,
//            128x128 tile, BK=32, 16x16x32 MFMA) — zero staging VALU.

#define M_DIM 8192
#define N_DIM 4096
#define K_DIM 4096
#define NBLK  128   // N / 32

typedef __attribute__((ext_vector_type(8))) short short8;   // 8 bf16
typedef __attribute__((ext_vector_type(4))) float f32x4;

typedef const __attribute__((address_space(1))) unsigned char* gas;
typedef __attribute__((address_space(3))) unsigned char* las;

// Pack two fp32 into two bf16 (RNE): low = a, high = b.
__device__ __forceinline__ unsigned pk_bf16(float a, float b) {
  unsigned ua = __builtin_bit_cast(unsigned, a);
  unsigned ub = __builtin_bit_cast(unsigned, b);
  ua += 0x7fffu + ((ua >> 16) & 1u);
  ub += 0x7fffu + ((ub >> 16) & 1u);
  return (ua >> 16) | (ub & 0xffff0000u);
}

// ---------------- pass 1a: A fp32 -> bf16 ----------------
__global__ __launch_bounds__(256)
void a_to_bf16(const float* __restrict__ A, ushort* __restrict__ Abf) {
  const long idx = ((long)blockIdx.x * 256 + threadIdx.x) * 8;
  const float4 v0 = *(const float4*)(A + idx);
  const float4 v1 = *(const float4*)(A + idx + 4);
  uint4 p;
  p.x = pk_bf16(v0.x, v0.y);
  p.y = pk_bf16(v0.z, v0.w);
  p.z = pk_bf16(v1.x, v1.y);
  p.w = pk_bf16(v1.z, v1.w);
  *(uint4*)(Abf + idx) = p;
}

// ------- pass 1b: dequant + transpose: Q[K][N] -> Wt[N][K] bf16 -------
// 64x64 tiles through LDS. Row stride 68 ushorts: load-phase ushort stores
// hit banks 2*nl mod 32 (2-way, free per m136); store-phase b64 reads are
// uniform 4/bank (minimum).
__global__ __launch_bounds__(256)
void dequant_transpose(const int* __restrict__ Q, const float* __restrict__ S,
                       ushort* __restrict__ Wt) {
  __shared__ ushort T[64 * 68];
  const int k0 = blockIdx.y * 64;
  const int n0 = blockIdx.x * 64;
  const int t = threadIdx.x;
  const int nl = t & 63;        // lane-over-n: coalesced Q reads
  const int kb = t >> 6;        // 0..3

  const float sscale = S[0] * 0.0f; // (unused guard removed by compiler)
  (void)sscale;

  #pragma unroll
  for (int i = 0; i < 16; ++i) {
    const int kl = kb + i * 4;
    const int k = k0 + kl;
    const int q = Q[(long)k * N_DIM + n0 + nl];
    const float s = S[k * NBLK + ((n0 + nl) >> 5)];
    const float w = (float)q * s;
    unsigned u = __builtin_bit_cast(unsigned, w);
    u += 0x7fffu + ((u >> 16) & 1u);
    T[nl * 68 + kl] = (ushort)(u >> 16);
  }
  __syncthreads();

  const int n = t >> 2;             // 0..63
  const int kc = (t & 3) * 16;      // 0,16,32,48
  const ushort* src = &T[n * 68 + kc];
  uint2 a = *(const uint2*)(src + 0);
  uint2 b = *(const uint2*)(src + 4);
  uint2 c = *(const uint2*)(src + 8);
  uint2 d = *(const uint2*)(src + 12);
  uint4 o0 = {a.x, a.y, b.x, b.y};
  uint4 o1 = {c.x, c.y, d.x, d.y};
  ushort* dst = Wt + (long)(n0 + n) * K_DIM + k0 + kc;
  *(uint4*)(dst + 0) = o0;
  *(uint4*)(dst + 8) = o1;
}

// ---------------- pass 2: m97-structure bf16 GEMM ----------------
// A[M][K] bf16, Wt[N][K] bf16 (i.e. B^T), C[M][N] fp32 += bias.
// 128x128 tile, BK=32, 4 waves each computing 64x64 via 4x4 16x16x32 MFMA.
__global__ __launch_bounds__(256)
void gemm_bf16(const ushort* __restrict__ Abf, const ushort* __restrict__ Wt,
               const float* __restrict__ bias, float* __restrict__ C) {
  __shared__ __align__(16) ushort Alds[128 * 32];
  __shared__ __align__(16) ushort Blds[128 * 32];

  const int tid = threadIdx.x;
  const int m0 = blockIdx.y * 128;
  const int n0 = blockIdx.x * 128;
  const int wave = tid >> 6;
  const int lane = tid & 63;
  const int wm = (wave >> 1) * 64;
  const int wn = (wave & 1) * 64;
  const int lrow = lane & 15;
  const int quad = lane >> 4;

  // Staging map: wave w instr i stages rows [w*16 + i*64, +16), lane l ->
  // row w*16+i*64+(l>>2), k-chunk (l&3)*8. LDS lands at wavebase + l*16B,
  // which is exactly row-major [row][k] contiguous (no padding allowed —
  // global_load_lds writes wave-uniform base + lane*16).
  const int srow = wave * 16 + (lane >> 2);
  const int skoff = (lane & 3) * 8;

  const ushort* Ag0 = Abf + (long)(m0 + srow) * K_DIM + skoff;
  const ushort* Ag1 = Ag0 + (long)64 * K_DIM;
  const ushort* Bg0 = Wt + (long)(n0 + srow) * K_DIM + skoff;
  const ushort* Bg1 = Bg0 + (long)64 * K_DIM;

  ushort* Al0 = &Alds[wave * 512];
  ushort* Al1 = &Alds[wave * 512 + 2048];
  ushort* Bl0 = &Blds[wave * 512];
  ushort* Bl1 = &Blds[wave * 512 + 2048];

  f32x4 acc[4][4];
  #pragma unroll
  for (int i = 0; i < 4; ++i)
    #pragma unroll
    for (int j = 0; j < 4; ++j)
      acc[i][j] = (f32x4){0.f, 0.f, 0.f, 0.f};

  for (int k0 = 0; k0 < K_DIM; k0 += 32) {
    __builtin_amdgcn_global_load_lds((gas)(Ag0 + k0), (las)Al0, 16, 0, 0);
    __builtin_amdgcn_global_load_lds((gas)(Ag1 + k0), (las)Al1, 16, 0, 0);
    __builtin_amdgcn_global_load_lds((gas)(Bg0 + k0), (las)Bl0, 16, 0, 0);
    __builtin_amdgcn_global_load_lds((gas)(Bg1 + k0), (las)Bl1, 16, 0, 0);
    __syncthreads();

    short8 afrag[4], bfrag[4];
    #pragma unroll
    for (int t = 0; t < 4; ++t) {
      afrag[t] = *(const short8*)&Alds[(wm + t * 16 + lrow) * 32 + quad * 8];
      bfrag[t] = *(const short8*)&Blds[(wn + t * 16 + lrow) * 32 + quad * 8];
    }
    #pragma unroll
    for (int mt = 0; mt < 4; ++mt)
      #pragma unroll
      for (int nt = 0; nt < 4; ++nt)
        acc[mt][nt] = __builtin_amdgcn_mfma_f32_16x16x32_bf16(afrag[mt], bfrag[nt],
                                                              acc[mt][nt], 0, 0, 0);
    __syncthreads();
  }

  // Epilogue: C/D layout row = quad*4+reg, col = lane&15 (verified r1).
  #pragma unroll
  for (int nt = 0; nt < 4; ++nt) {
    const int n = n0 + wn + nt * 16 + lrow;
    const float bv = bias[n];
    #pragma unroll
    for (int mt = 0; mt < 4; ++mt) {
      const int mbase = m0 + wm + mt * 16 + quad * 4;
      #pragma unroll
      for (int r = 0; r < 4; ++r) {
        C[(long)(mbase + r) * N_DIM + n] = acc[mt][nt][r] + bv;
      }
    }
  }
}

// ---------------- fallback (round-1 fused kernel) ----------------
__global__ __launch_bounds__(256)
void gguf_gemm_fused(const float* __restrict__ A, const int* __restrict__ Q,
                     const float* __restrict__ S, const float* __restrict__ bias,
                     float* __restrict__ C) {
  __shared__ __align__(16) ushort Alds[128 * 32];
  __shared__ __align__(16) ushort Blds[128 * 32];
  const int tid = threadIdx.x;
  const int m0 = blockIdx.y * 128;
  const int n0 = blockIdx.x * 128;
  const int wave = tid >> 6, lane = tid & 63;
  const int wm = (wave >> 1) * 64, wn = (wave & 1) * 64;
  const int lrow = lane & 15, quad = lane >> 4;
  const int ar = tid >> 2, ac = (tid & 3) * 4;
  const int c8a = ((ar >> 1) & 3) << 3;
  const int bn = tid & 127, bkc = (tid >> 7) * 16;
  const int c8b = ((bn >> 1) & 3) << 3;
  const float* Abase = A + (long)(m0 + ar) * K_DIM + ac;
  const int* Qbase = Q + (long)bkc * N_DIM + n0 + bn;
  const float* Sbase = S + (long)bkc * NBLK + ((n0 + bn) >> 5);
  f32x4 acc[4][4];
  #pragma unroll
  for (int i = 0; i < 4; ++i)
    #pragma unroll
    for (int j = 0; j < 4; ++j) acc[i][j] = (f32x4){0.f, 0.f, 0.f, 0.f};
  for (int k0 = 0; k0 < K_DIM; k0 += 32) {
    #pragma unroll
    for (int i = 0; i < 2; ++i)
      #pragma unroll
      for (int j = 0; j < 2; ++j) {
        const float4 v = *(const float4*)(Abase + (long)i * 64 * K_DIM + k0 + j * 16);
        uint2 p; p.x = pk_bf16(v.x, v.y); p.y = pk_bf16(v.z, v.w);
        const int k = ac + j * 16;
        *(uint2*)&Alds[(ar + i * 64) * 32 + (k ^ c8a)] = p;
      }
    {
      const int* qp = Qbase + (long)k0 * N_DIM;
      const float* sp = Sbase + (long)k0 * NBLK;
      unsigned w[8];
      #pragma unroll
      for (int i = 0; i < 8; ++i) {
        const int q0 = qp[(2 * i) * N_DIM];
        const int q1 = qp[(2 * i + 1) * N_DIM];
        const float s0 = sp[(2 * i) * NBLK];
        const float s1 = sp[(2 * i + 1) * NBLK];
        w[i] = pk_bf16((float)q0 * s0, (float)q1 * s1);
      }
      uint4 g0 = {w[0], w[1], w[2], w[3]};
      uint4 g1 = {w[4], w[5], w[6], w[7]};
      *(uint4*)&Blds[bn * 32 + (bkc ^ c8b)] = g0;
      *(uint4*)&Blds[bn * 32 + ((bkc + 8) ^ c8b)] = g1;
    }
    __syncthreads();
    short8 afrag[4], bfrag[4];
    #pragma unroll
    for (int t = 0; t < 4; ++t) {
      const int mrow = wm + t * 16 + lrow;
      afrag[t] = *(const short8*)&Alds[mrow * 32 + ((quad * 8) ^ (((mrow >> 1) & 3) << 3))];
      const int nrow = wn + t * 16 + lrow;
      bfrag[t] = *(const short8*)&Blds[nrow * 32 + ((quad * 8) ^ (((nrow >> 1) & 3) << 3))];
    }
    #pragma unroll
    for (int mt = 0; mt < 4; ++mt)
      #pragma unroll
      for (int nt = 0; nt < 4; ++nt)
        acc[mt][nt] = __builtin_amdgcn_mfma_f32_16x16x32_bf16(afrag[mt], bfrag[nt],
                                                              acc[mt][nt], 0, 0, 0);
    __syncthreads();
  }
  #pragma unroll
  for (int nt = 0; nt < 4; ++nt) {
    const int n = n0 + wn + nt * 16 + lrow;
    const float bv = bias[n];
    #pragma unroll
    for (int mt = 0; mt < 4; ++mt) {
      const int mbase = m0 + wm + mt * 16 + quad * 4;
      #pragma unroll
      for (int r = 0; r < 4; ++r)
        C[(long)(mbase + r) * N_DIM + n] = acc[mt][nt][r] + bv;
    }
  }
}

extern "C" void kernel_launch(void* const* d_in, const int* in_sizes, int n_in,
                              void* d_out, int out_size, void* d_ws, size_t ws_size,
                              hipStream_t stream) {
  const float* A    = (const float*)d_in[0];
  const int*   Q    = (const int*)d_in[1];
  const float* S    = (const float*)d_in[2];
  const float* bias = (const float*)d_in[3];
  float* C = (float*)d_out;

  const size_t abf_bytes = (size_t)M_DIM * K_DIM * 2;   // 64 MiB
  const size_t wt_bytes  = (size_t)N_DIM * K_DIM * 2;   // 32 MiB

  if (ws_size >= abf_bytes + wt_bytes) {
    ushort* Abf = (ushort*)d_ws;
    ushort* Wt  = (ushort*)((char*)d_ws + abf_bytes);
    a_to_bf16<<<(M_DIM * (long)K_DIM) / (256 * 8), 256, 0, stream>>>(A, Abf);
    dim3 gt(N_DIM / 64, K_DIM / 64);
    dequant_transpose<<<gt, 256, 0, stream>>>(Q, S, Wt);
    dim3 grid(N_DIM / 128, M_DIM / 128);
    gemm_bf16<<<grid, 256, 0, stream>>>(Abf, Wt, bias, C);
  } else {
    dim3 grid(N_DIM / 128, M_DIM / 128);
    gguf_gemm_fused<<<grid, 256, 0, stream>>>(A, Q, S, bias, C);
  }
}